// Round 4
// baseline (316.535 us; speedup 1.0000x reference)
//
#include <hip/hip_runtime.h>
#include <stdint.h>

#define NS 4096
#define DIM 2048
#define MARGINF 0.3f

typedef __bf16 bf16x8 __attribute__((ext_vector_type(8)));
typedef float floatx4 __attribute__((ext_vector_type(4)));

__device__ __forceinline__ unsigned short f2bf_rne(float x) {
  unsigned u = __float_as_uint(x);
  u += 0x7FFFu + ((u >> 16) & 1u);
  return (unsigned short)(u >> 16);
}
__device__ __forceinline__ float bf2f(unsigned short b) {
  return __uint_as_float(((unsigned)b) << 16);
}

// ---------------- kernel 1: fp32 -> bf16 convert + row norms + init ----------------
__global__ __launch_bounds__(256) void prep_kernel(
    const float* __restrict__ X, unsigned short* __restrict__ Xbf,
    float* __restrict__ sq, unsigned long long* __restrict__ posP,
    unsigned long long* __restrict__ negP, float* __restrict__ sums) {
  const int row = blockIdx.x;
  const int t = threadIdx.x;
  const float4* xr = (const float4*)(X + (size_t)row * DIM);
  ushort4* br = (ushort4*)(Xbf + (size_t)row * DIM);
  float s = 0.f;
#pragma unroll
  for (int it = 0; it < 2; ++it) {
    int i = t + it * 256;
    float4 v = xr[i];
    ushort4 o;
    o.x = f2bf_rne(v.x); o.y = f2bf_rne(v.y);
    o.z = f2bf_rne(v.z); o.w = f2bf_rne(v.w);
    // accumulate norm of the ROUNDED values so d2 is consistent with the MFMA dot
    float b0 = bf2f(o.x), b1 = bf2f(o.y), b2 = bf2f(o.z), b3 = bf2f(o.w);
    s += b0 * b0 + b1 * b1 + b2 * b2 + b3 * b3;
    br[i] = o;
  }
#pragma unroll
  for (int m = 32; m > 0; m >>= 1) s += __shfl_down(s, m, 64);
  __shared__ float ls[4];
  const int w = t >> 6, lane = t & 63;
  if (lane == 0) ls[w] = s;
  __syncthreads();
  if (t == 0) {
    sq[row] = ls[0] + ls[1] + ls[2] + ls[3];
    posP[row] = 0ULL;              // max-init (dist >= 0, self always positive)
    negP[row] = ~0ULL;             // min-init
    if (row == 0) { sums[0] = 0.f; sums[1] = 0.f; }
  }
}

// ---------------- kernel 2: register-direct bf16 MFMA Gram GEMM (upper triangle) ----------------
// No LDS, no __syncthreads in the K-loop: each lane loads its MFMA fragments
// directly from global. Lanes {L, L+16, L+32, L+48} of a fragment cover one
// contiguous 64B line per row, so coalescing is perfect; waves pipeline
// independently (compiler-managed vmcnt), no barrier drain.
#define BM 128
#define BN 128
#define BK 32
#define NT 32
#define NBLK (NT * (NT + 1) / 2)   // 528 upper-tri tiles

__global__ __launch_bounds__(256) void gemm_mine_kernel(
    const unsigned short* __restrict__ Xbf, const float* __restrict__ sq,
    const int* __restrict__ targets,
    unsigned long long* __restrict__ posP, unsigned long long* __restrict__ negP) {
  // invert t -> (ty, tx) on the upper triangle
  const int t = blockIdx.x;
  int ty = (int)((65.0f - sqrtf((float)(4225 - 8 * t))) * 0.5f);
  while ((ty + 1) * (65 - (ty + 1)) / 2 <= t) ++ty;
  while (ty * (65 - ty) / 2 > t) --ty;
  const int tx = ty + (t - ty * (65 - ty) / 2);
  const int r0 = ty * BM;
  const int c0 = tx * BN;

  const int tid = threadIdx.x;
  const int lane = tid & 63;
  const int w = tid >> 6;
  const int wm = w >> 1, wn = w & 1;
  const int quad = lane >> 4;
  const int ml = lane & 15;

  floatx4 acc[4][4];
#pragma unroll
  for (int i = 0; i < 4; ++i)
#pragma unroll
    for (int j = 0; j < 4; ++j)
#pragma unroll
      for (int k = 0; k < 4; ++k) acc[i][j][k] = 0.f;

  // per-lane fragment base pointers (advance 32 elems = 64 B per K-step)
  const unsigned short* pA[4];
  const unsigned short* pB[4];
#pragma unroll
  for (int i = 0; i < 4; ++i) {
    pA[i] = Xbf + (size_t)(r0 + wm * 64 + ml + i * 16) * DIM + quad * 8;
    pB[i] = Xbf + (size_t)(c0 + wn * 64 + ml + i * 16) * DIM + quad * 8;
  }

  // 2-stage register rotation so loads of step k+1 overlap MFMA of step k
  bf16x8 a0[4], b0[4], a1[4], b1[4];
#pragma unroll
  for (int i = 0; i < 4; ++i) { a0[i] = *(const bf16x8*)(pA[i]); b0[i] = *(const bf16x8*)(pB[i]); }

  for (int k0 = 0; k0 < DIM; k0 += 2 * BK) {
    const int kn1 = k0 + BK;
#pragma unroll
    for (int i = 0; i < 4; ++i) {
      a1[i] = *(const bf16x8*)(pA[i] + kn1);
      b1[i] = *(const bf16x8*)(pB[i] + kn1);
    }
#pragma unroll
    for (int i = 0; i < 4; ++i)
#pragma unroll
      for (int j = 0; j < 4; ++j)
        acc[i][j] = __builtin_amdgcn_mfma_f32_16x16x32_bf16(a0[i], b0[j], acc[i][j], 0, 0, 0);
    const int kn2 = k0 + 2 * BK;
    if (kn2 < DIM) {
#pragma unroll
      for (int i = 0; i < 4; ++i) {
        a0[i] = *(const bf16x8*)(pA[i] + kn2);
        b0[i] = *(const bf16x8*)(pB[i] + kn2);
      }
    }
#pragma unroll
    for (int i = 0; i < 4; ++i)
#pragma unroll
      for (int j = 0; j < 4; ++j)
        acc[i][j] = __builtin_amdgcn_mfma_f32_16x16x32_bf16(a1[i], b1[j], acc[i][j], 0, 0, 0);
  }

  // epilogue A: row-direction mining (rows gr, cols gc).
  // C/D layout: col = lane&15, row = (lane>>4)*4 + reg  [m89/m91 verified]
  const int cl = ml;
  const int tr_base = r0 + wm * 64;
  const int tc_base = c0 + wn * 64;
#pragma unroll
  for (int i = 0; i < 4; ++i) {
#pragma unroll
    for (int rg = 0; rg < 4; ++rg) {
      const int gr = tr_base + i * 16 + quad * 4 + rg;
      const int tgt_r = targets[gr];
      const float sqr = sq[gr];
      unsigned long long pm = 0ULL;
      unsigned long long nm = ~0ULL;
#pragma unroll
      for (int j = 0; j < 4; ++j) {
        const int gc = tc_base + j * 16 + cl;
        const float dot = acc[i][j][rg];
        const float d2 = sqr + sq[gc] - 2.0f * dot;
        const float dist = sqrtf(fmaxf(d2, 1e-12f));
        const unsigned long long packed_hi = ((unsigned long long)__float_as_uint(dist)) << 32;
        if (targets[gc] == tgt_r) {
          // argmax first-index tiebreak: larger (4095-gc) == smaller gc wins on ties
          unsigned long long cand = packed_hi | (unsigned)(4095 - gc);
          pm = pm > cand ? pm : cand;
        } else {
          unsigned long long cand = packed_hi | (unsigned)gc;
          nm = nm < cand ? nm : cand;
        }
      }
#pragma unroll
      for (int m = 1; m < 16; m <<= 1) {
        unsigned long long pmo = __shfl_xor(pm, m, 64);
        unsigned long long nmo = __shfl_xor(nm, m, 64);
        pm = pm > pmo ? pm : pmo;
        nm = nm < nmo ? nm : nmo;
      }
      if (cl == 0) {
        atomicMax(&posP[gr], pm);
        atomicMin(&negP[gr], nm);
      }
    }
  }

  // epilogue B: transposed mining for off-diagonal blocks — bit-exact symmetric reuse
  if (tx != ty) {
#pragma unroll
    for (int j = 0; j < 4; ++j) {
      const int gc = tc_base + j * 16 + cl;
      const int tgt_c = targets[gc];
      const float sqc = sq[gc];
      unsigned long long pm = 0ULL;
      unsigned long long nm = ~0ULL;
#pragma unroll
      for (int i = 0; i < 4; ++i) {
#pragma unroll
        for (int rg = 0; rg < 4; ++rg) {
          const int gr = tr_base + i * 16 + quad * 4 + rg;
          const float dot = acc[i][j][rg];
          const float d2 = sq[gr] + sqc - 2.0f * dot;
          const float dist = sqrtf(fmaxf(d2, 1e-12f));
          const unsigned long long packed_hi = ((unsigned long long)__float_as_uint(dist)) << 32;
          if (targets[gr] == tgt_c) {
            unsigned long long cand = packed_hi | (unsigned)(4095 - gr);
            pm = pm > cand ? pm : cand;
          } else {
            unsigned long long cand = packed_hi | (unsigned)gr;
            nm = nm < cand ? nm : cand;
          }
        }
      }
#pragma unroll
      for (int m = 16; m < 64; m <<= 1) {
        unsigned long long pmo = __shfl_xor(pm, m, 64);
        unsigned long long nmo = __shfl_xor(nm, m, 64);
        pm = pm > pmo ? pm : pmo;
        nm = nm < nmo ? nm : nmo;
      }
      if (quad == 0) {
        atomicMax(&posP[gc], pm);
        atomicMin(&negP[gc], nm);
      }
    }
  }
}

// ---------------- kernel 3: local DTW distances + both loss sums ----------------
__global__ __launch_bounds__(256) void local_dtw_kernel(
    const float* __restrict__ LF, const unsigned long long* __restrict__ posP,
    const unsigned long long* __restrict__ negP, float* __restrict__ sums) {
  __shared__ float bufA[4][1024];
  __shared__ float bufP[4][1024];
  __shared__ float bufN[4][1024];
  __shared__ float dmP[4][64];
  __shared__ float dmN[4][64];
  __shared__ float gterms[4], lterms[4];
  const int w = threadIdx.x >> 6, lane = threadIdx.x & 63;
  const int a = blockIdx.x * 4 + w;
  const unsigned long long pp = posP[a];
  const unsigned long long nn = negP[a];
  const int p_ind = 4095 - (int)(pp & 0xFFFFFFFFULL);
  const int n_ind = (int)(nn & 0xFFFFFFFFULL);
  const float dist_ap = __uint_as_float((unsigned)(pp >> 32));
  const float dist_an = __uint_as_float((unsigned)(nn >> 32));

  const float4* ga = (const float4*)(LF + (size_t)a * 1024);
  const float4* gp = (const float4*)(LF + (size_t)p_ind * 1024);
  const float4* gn = (const float4*)(LF + (size_t)n_ind * 1024);
  float4* la = (float4*)bufA[w];
  float4* lp = (float4*)bufP[w];
  float4* ln_ = (float4*)bufN[w];
#pragma unroll
  for (int i = 0; i < 4; ++i) {
    la[lane + i * 64] = ga[lane + i * 64];
    lp[lane + i * 64] = gp[lane + i * 64];
    ln_[lane + i * 64] = gn[lane + i * 64];
  }
  __syncthreads();
  // lane -> (t1, t2) pair of the 8x8 cross-distance matrix; layout is [d][t] (stride 8)
  const int t1 = lane >> 3, t2 = lane & 7;
  float sp = 0.f, sn = 0.f;
#pragma unroll 8
  for (int d = 0; d < 128; ++d) {
    float xa = bufA[w][d * 8 + t1];
    float xp = bufP[w][d * 8 + t2];
    float xn = bufN[w][d * 8 + t2];
    float e1 = xa - xp; sp += e1 * e1;
    float e2 = xa - xn; sn += e2 * e2;
  }
  float ddp = sqrtf(fmaxf(sp, 1e-12f));
  float ddn = sqrtf(fmaxf(sn, 1e-12f));
  dmP[w][lane] = tanhf(0.5f * ddp);   // == (e^d-1)/(e^d+1)
  dmN[w][lane] = tanhf(0.5f * ddn);
  __syncthreads();
  if (lane == 0) {
    float ap, an;
    {
      const float* dm = dmP[w];
      float row[8];
      row[0] = dm[0];
#pragma unroll
      for (int j = 1; j < 8; ++j) row[j] = row[j - 1] + dm[j];
#pragma unroll
      for (int i = 1; i < 8; ++i) {
        row[0] = row[0] + dm[i * 8];
#pragma unroll
        for (int j = 1; j < 8; ++j) row[j] = fminf(row[j], row[j - 1]) + dm[i * 8 + j];
      }
      ap = row[7];
    }
    {
      const float* dm = dmN[w];
      float row[8];
      row[0] = dm[0];
#pragma unroll
      for (int j = 1; j < 8; ++j) row[j] = row[j - 1] + dm[j];
#pragma unroll
      for (int i = 1; i < 8; ++i) {
        row[0] = row[0] + dm[i * 8];
#pragma unroll
        for (int j = 1; j < 8; ++j) row[j] = fminf(row[j], row[j - 1]) + dm[i * 8 + j];
      }
      an = row[7];
    }
    gterms[w] = fmaxf(dist_ap - dist_an + MARGINF, 0.f);
    lterms[w] = fmaxf(ap - an + MARGINF, 0.f);
  }
  __syncthreads();
  if (threadIdx.x == 0) {
    atomicAdd(&sums[0], gterms[0] + gterms[1] + gterms[2] + gterms[3]);
    atomicAdd(&sums[1], lterms[0] + lterms[1] + lterms[2] + lterms[3]);
  }
}

// ---------------- kernel 4: finalize ----------------
__global__ void finalize_kernel(const float* __restrict__ sums, float* __restrict__ out) {
  if (threadIdx.x == 0) {
    out[0] = sums[0] * (1.0f / 4096.0f);
    out[1] = sums[1] * (1.0f / 4096.0f);
  }
}

extern "C" void kernel_launch(void* const* d_in, const int* in_sizes, int n_in,
                              void* d_out, int out_size, void* d_ws, size_t ws_size,
                              hipStream_t stream) {
  const float* X = (const float*)d_in[0];
  const int* targets = (const int*)d_in[1];
  const float* LF = (const float*)d_in[2];
  float* out = (float*)d_out;

  char* ws = (char*)d_ws;
  size_t off = 0;
  unsigned short* Xbf = (unsigned short*)(ws + off); off += (size_t)NS * DIM * 2;  // 16 MB
  float* sq = (float*)(ws + off); off += (size_t)NS * 4;
  off = (off + 255) & ~(size_t)255;
  unsigned long long* posP = (unsigned long long*)(ws + off); off += (size_t)NS * 8;
  unsigned long long* negP = (unsigned long long*)(ws + off); off += (size_t)NS * 8;
  float* sums = (float*)(ws + off); off += 256;

  prep_kernel<<<NS, 256, 0, stream>>>(X, Xbf, sq, posP, negP, sums);
  gemm_mine_kernel<<<NBLK, 256, 0, stream>>>(Xbf, sq, targets, posP, negP);
  local_dtw_kernel<<<NS / 4, 256, 0, stream>>>(LF, posP, negP, sums);
  finalize_kernel<<<1, 64, 0, stream>>>(sums, out);
}

// Round 5
// 243.822 us; speedup vs baseline: 1.2982x; 1.2982x over previous
//
#include <hip/hip_runtime.h>
#include <stdint.h>

#define NS 4096
#define DIM 2048
#define MARGINF 0.3f

typedef __bf16 bf16x8 __attribute__((ext_vector_type(8)));
typedef float floatx4 __attribute__((ext_vector_type(4)));

#define GLOBAL_AS __attribute__((address_space(1)))
#define LDS_AS __attribute__((address_space(3)))

// s_waitcnt with vmcnt(N), lgkmcnt/expcnt unconstrained (gfx9 encoding)
#define WAITVM(N) __builtin_amdgcn_s_waitcnt((N) | (7 << 4) | (15 << 8))

__device__ __forceinline__ unsigned short f2bf_rne(float x) {
  unsigned u = __float_as_uint(x);
  u += 0x7FFFu + ((u >> 16) & 1u);
  return (unsigned short)(u >> 16);
}
__device__ __forceinline__ float bf2f(unsigned short b) {
  return __uint_as_float(((unsigned)b) << 16);
}

// ---------------- kernel 1: fp32 -> bf16 convert + row norms + init ----------------
__global__ __launch_bounds__(256) void prep_kernel(
    const float* __restrict__ X, unsigned short* __restrict__ Xbf,
    float* __restrict__ sq, unsigned long long* __restrict__ posP,
    unsigned long long* __restrict__ negP, float* __restrict__ sums) {
  const int row = blockIdx.x;
  const int t = threadIdx.x;
  const float4* xr = (const float4*)(X + (size_t)row * DIM);
  ushort4* br = (ushort4*)(Xbf + (size_t)row * DIM);
  float s = 0.f;
#pragma unroll
  for (int it = 0; it < 2; ++it) {
    int i = t + it * 256;
    float4 v = xr[i];
    ushort4 o;
    o.x = f2bf_rne(v.x); o.y = f2bf_rne(v.y);
    o.z = f2bf_rne(v.z); o.w = f2bf_rne(v.w);
    // accumulate norm of the ROUNDED values so d2 is consistent with the MFMA dot
    float b0 = bf2f(o.x), b1 = bf2f(o.y), b2 = bf2f(o.z), b3 = bf2f(o.w);
    s += b0 * b0 + b1 * b1 + b2 * b2 + b3 * b3;
    br[i] = o;
  }
#pragma unroll
  for (int m = 32; m > 0; m >>= 1) s += __shfl_down(s, m, 64);
  __shared__ float ls[4];
  const int w = t >> 6, lane = t & 63;
  if (lane == 0) ls[w] = s;
  __syncthreads();
  if (t == 0) {
    sq[row] = ls[0] + ls[1] + ls[2] + ls[3];
    posP[row] = 0ULL;              // max-init (dist >= 0, self always positive)
    negP[row] = ~0ULL;             // min-init
    if (row == 0) { sums[0] = 0.f; sums[1] = 0.f; }
  }
}

// ---------------- kernel 2: wave-private pipelined bf16 MFMA Gram GEMM ----------------
// One 64-thread block (= one wave) per 64x64 upper-triangular tile. All LDS is
// wave-private: NO __syncthreads anywhere. Double-buffered staging with manual
// s_waitcnt vmcnt(8): iter k+1's 8 global_load_lds stay in flight while iter k
// computes — the fine-grained pipeline the barrier structure cannot express.
#define BT 64            // tile dim
#define BK 32
#define NT (NS / BT)     // 64 tiles per dim
#define NBLK (NT * (NT + 1) / 2)   // 2080 upper-tri tiles

__device__ __forceinline__ void async16(const void* g, void* l) {
  __builtin_amdgcn_global_load_lds((GLOBAL_AS unsigned int*)g, (LDS_AS unsigned int*)l,
                                   16, 0, 0);
}

__global__ __launch_bounds__(64) void gemm_mine_kernel(
    const unsigned short* __restrict__ Xbf, const float* __restrict__ sq,
    const int* __restrict__ targets,
    unsigned long long* __restrict__ posP, unsigned long long* __restrict__ negP) {
  // invert t -> (ty, tx) on the upper triangle: cum(y) = y*(129-y)/2
  const int t = blockIdx.x;
  int ty = (int)((129.0f - sqrtf((float)(16641 - 8 * t))) * 0.5f);
  while ((ty + 1) * (129 - (ty + 1)) / 2 <= t) ++ty;
  while (ty * (129 - ty) / 2 > t) --ty;
  const int tx = ty + (t - ty * (129 - ty) / 2);
  const int r0 = ty * BT;
  const int c0 = tx * BT;

  // [buf][A/B][64 rows x 32 elems] = 16 KB, private to this wave
  __shared__ __align__(16) unsigned short lds[2][2][BT * BK];

  const int lane = threadIdx.x;
  const int quad = lane >> 4;
  const int ml = lane & 15;

  floatx4 acc[4][4];
#pragma unroll
  for (int i = 0; i < 4; ++i)
#pragma unroll
    for (int j = 0; j < 4; ++j)
#pragma unroll
      for (int k = 0; k < 4; ++k) acc[i][j][k] = 0.f;

  // staging lane map (XOR swizzle, measured 0 conflicts in R2/R3):
  // 16B chunk c of LDS row R lives at slot c ^ ((R>>1)&3); realized by permuting
  // which global chunk each lane fetches. rows per async16: q*16 + (lane>>2).
  const int r_rel = lane >> 2;
  const int c_g = (lane & 3) ^ ((lane >> 3) & 3);
  const unsigned short* gA = Xbf + (size_t)(r0 + r_rel) * DIM + c_g * 8;
  const unsigned short* gB = Xbf + (size_t)(c0 + r_rel) * DIM + c_g * 8;

  // fragment read chunk slot: quad ^ ((row>>1)&3), row = i*16+ml -> key = (ml>>1)&3
  const int koff = (quad ^ ((ml >> 1) & 3)) * 8;

#define ISSUE8(K0, BUF)                                                        \
  {                                                                            \
    _Pragma("unroll") for (int q = 0; q < 4; ++q)                              \
        async16(gA + (size_t)(q * 16) * DIM + (K0), &lds[BUF][0][q * 512]);    \
    _Pragma("unroll") for (int q = 0; q < 4; ++q)                              \
        async16(gB + (size_t)(q * 16) * DIM + (K0), &lds[BUF][1][q * 512]);    \
  }

  ISSUE8(0, 0);
  int cur = 0;
  for (int k0 = 0; k0 < DIM; k0 += BK) {
    if (k0 + BK < DIM) {
      ISSUE8(k0 + BK, cur ^ 1);
      WAITVM(8);    // iter-k loads done; iter-k+1's 8 remain in flight
    } else {
      WAITVM(0);    // final drain
    }
    bf16x8 af[4], bfr[4];
#pragma unroll
    for (int i = 0; i < 4; ++i)
      af[i] = *(const bf16x8*)(&lds[cur][0][(i * 16 + ml) * BK + koff]);
#pragma unroll
    for (int j = 0; j < 4; ++j)
      bfr[j] = *(const bf16x8*)(&lds[cur][1][(j * 16 + ml) * BK + koff]);
#pragma unroll
    for (int i = 0; i < 4; ++i)
#pragma unroll
      for (int j = 0; j < 4; ++j)
        acc[i][j] = __builtin_amdgcn_mfma_f32_16x16x32_bf16(af[i], bfr[j], acc[i][j], 0, 0, 0);
    cur ^= 1;
  }

  // epilogue A: row-direction mining (rows gr, cols gc).
  // C/D layout: col = lane&15, row = (lane>>4)*4 + reg  [m89/m91 verified]
  const int cl = ml;
#pragma unroll
  for (int i = 0; i < 4; ++i) {
#pragma unroll
    for (int rg = 0; rg < 4; ++rg) {
      const int gr = r0 + i * 16 + quad * 4 + rg;
      const int tgt_r = targets[gr];
      const float sqr = sq[gr];
      unsigned long long pm = 0ULL;
      unsigned long long nm = ~0ULL;
#pragma unroll
      for (int j = 0; j < 4; ++j) {
        const int gc = c0 + j * 16 + cl;
        const float dot = acc[i][j][rg];
        const float d2 = sqr + sq[gc] - 2.0f * dot;
        const float dist = sqrtf(fmaxf(d2, 1e-12f));
        const unsigned long long packed_hi = ((unsigned long long)__float_as_uint(dist)) << 32;
        if (targets[gc] == tgt_r) {
          // argmax first-index tiebreak: larger (4095-gc) == smaller gc wins on ties
          unsigned long long cand = packed_hi | (unsigned)(4095 - gc);
          pm = pm > cand ? pm : cand;
        } else {
          unsigned long long cand = packed_hi | (unsigned)gc;
          nm = nm < cand ? nm : cand;
        }
      }
#pragma unroll
      for (int m = 1; m < 16; m <<= 1) {
        unsigned long long pmo = __shfl_xor(pm, m, 64);
        unsigned long long nmo = __shfl_xor(nm, m, 64);
        pm = pm > pmo ? pm : pmo;
        nm = nm < nmo ? nm : nmo;
      }
      if (cl == 0) {
        atomicMax(&posP[gr], pm);
        atomicMin(&negP[gr], nm);
      }
    }
  }

  // epilogue B: transposed mining for off-diagonal blocks — bit-exact symmetric reuse
  if (tx != ty) {
#pragma unroll
    for (int j = 0; j < 4; ++j) {
      const int gc = c0 + j * 16 + cl;
      const int tgt_c = targets[gc];
      const float sqc = sq[gc];
      unsigned long long pm = 0ULL;
      unsigned long long nm = ~0ULL;
#pragma unroll
      for (int i = 0; i < 4; ++i) {
#pragma unroll
        for (int rg = 0; rg < 4; ++rg) {
          const int gr = r0 + i * 16 + quad * 4 + rg;
          const float dot = acc[i][j][rg];
          const float d2 = sq[gr] + sqc - 2.0f * dot;
          const float dist = sqrtf(fmaxf(d2, 1e-12f));
          const unsigned long long packed_hi = ((unsigned long long)__float_as_uint(dist)) << 32;
          if (targets[gr] == tgt_c) {
            unsigned long long cand = packed_hi | (unsigned)(4095 - gr);
            pm = pm > cand ? pm : cand;
          } else {
            unsigned long long cand = packed_hi | (unsigned)gr;
            nm = nm < cand ? nm : cand;
          }
        }
      }
#pragma unroll
      for (int m = 16; m < 64; m <<= 1) {
        unsigned long long pmo = __shfl_xor(pm, m, 64);
        unsigned long long nmo = __shfl_xor(nm, m, 64);
        pm = pm > pmo ? pm : pmo;
        nm = nm < nmo ? nm : nmo;
      }
      if (quad == 0) {
        atomicMax(&posP[gc], pm);
        atomicMin(&negP[gc], nm);
      }
    }
  }
}

// ---------------- kernel 3: local DTW distances + both loss sums ----------------
__global__ __launch_bounds__(256) void local_dtw_kernel(
    const float* __restrict__ LF, const unsigned long long* __restrict__ posP,
    const unsigned long long* __restrict__ negP, float* __restrict__ sums) {
  __shared__ float bufA[4][1024];
  __shared__ float bufP[4][1024];
  __shared__ float bufN[4][1024];
  __shared__ float dmP[4][64];
  __shared__ float dmN[4][64];
  __shared__ float gterms[4], lterms[4];
  const int w = threadIdx.x >> 6, lane = threadIdx.x & 63;
  const int a = blockIdx.x * 4 + w;
  const unsigned long long pp = posP[a];
  const unsigned long long nn = negP[a];
  const int p_ind = 4095 - (int)(pp & 0xFFFFFFFFULL);
  const int n_ind = (int)(nn & 0xFFFFFFFFULL);
  const float dist_ap = __uint_as_float((unsigned)(pp >> 32));
  const float dist_an = __uint_as_float((unsigned)(nn >> 32));

  const float4* ga = (const float4*)(LF + (size_t)a * 1024);
  const float4* gp = (const float4*)(LF + (size_t)p_ind * 1024);
  const float4* gn = (const float4*)(LF + (size_t)n_ind * 1024);
  float4* la = (float4*)bufA[w];
  float4* lp = (float4*)bufP[w];
  float4* ln_ = (float4*)bufN[w];
#pragma unroll
  for (int i = 0; i < 4; ++i) {
    la[lane + i * 64] = ga[lane + i * 64];
    lp[lane + i * 64] = gp[lane + i * 64];
    ln_[lane + i * 64] = gn[lane + i * 64];
  }
  __syncthreads();
  // lane -> (t1, t2) pair of the 8x8 cross-distance matrix; layout is [d][t] (stride 8)
  const int t1 = lane >> 3, t2 = lane & 7;
  float sp = 0.f, sn = 0.f;
#pragma unroll 8
  for (int d = 0; d < 128; ++d) {
    float xa = bufA[w][d * 8 + t1];
    float xp = bufP[w][d * 8 + t2];
    float xn = bufN[w][d * 8 + t2];
    float e1 = xa - xp; sp += e1 * e1;
    float e2 = xa - xn; sn += e2 * e2;
  }
  float ddp = sqrtf(fmaxf(sp, 1e-12f));
  float ddn = sqrtf(fmaxf(sn, 1e-12f));
  dmP[w][lane] = tanhf(0.5f * ddp);   // == (e^d-1)/(e^d+1)
  dmN[w][lane] = tanhf(0.5f * ddn);
  __syncthreads();
  if (lane == 0) {
    float ap, an;
    {
      const float* dm = dmP[w];
      float row[8];
      row[0] = dm[0];
#pragma unroll
      for (int j = 1; j < 8; ++j) row[j] = row[j - 1] + dm[j];
#pragma unroll
      for (int i = 1; i < 8; ++i) {
        row[0] = row[0] + dm[i * 8];
#pragma unroll
        for (int j = 1; j < 8; ++j) row[j] = fminf(row[j], row[j - 1]) + dm[i * 8 + j];
      }
      ap = row[7];
    }
    {
      const float* dm = dmN[w];
      float row[8];
      row[0] = dm[0];
#pragma unroll
      for (int j = 1; j < 8; ++j) row[j] = row[j - 1] + dm[j];
#pragma unroll
      for (int i = 1; i < 8; ++i) {
        row[0] = row[0] + dm[i * 8];
#pragma unroll
        for (int j = 1; j < 8; ++j) row[j] = fminf(row[j], row[j - 1]) + dm[i * 8 + j];
      }
      an = row[7];
    }
    gterms[w] = fmaxf(dist_ap - dist_an + MARGINF, 0.f);
    lterms[w] = fmaxf(ap - an + MARGINF, 0.f);
  }
  __syncthreads();
  if (threadIdx.x == 0) {
    atomicAdd(&sums[0], gterms[0] + gterms[1] + gterms[2] + gterms[3]);
    atomicAdd(&sums[1], lterms[0] + lterms[1] + lterms[2] + lterms[3]);
  }
}

// ---------------- kernel 4: finalize ----------------
__global__ void finalize_kernel(const float* __restrict__ sums, float* __restrict__ out) {
  if (threadIdx.x == 0) {
    out[0] = sums[0] * (1.0f / 4096.0f);
    out[1] = sums[1] * (1.0f / 4096.0f);
  }
}

extern "C" void kernel_launch(void* const* d_in, const int* in_sizes, int n_in,
                              void* d_out, int out_size, void* d_ws, size_t ws_size,
                              hipStream_t stream) {
  const float* X = (const float*)d_in[0];
  const int* targets = (const int*)d_in[1];
  const float* LF = (const float*)d_in[2];
  float* out = (float*)d_out;

  char* ws = (char*)d_ws;
  size_t off = 0;
  unsigned short* Xbf = (unsigned short*)(ws + off); off += (size_t)NS * DIM * 2;  // 16 MB
  float* sq = (float*)(ws + off); off += (size_t)NS * 4;
  off = (off + 255) & ~(size_t)255;
  unsigned long long* posP = (unsigned long long*)(ws + off); off += (size_t)NS * 8;
  unsigned long long* negP = (unsigned long long*)(ws + off); off += (size_t)NS * 8;
  float* sums = (float*)(ws + off); off += 256;

  prep_kernel<<<NS, 256, 0, stream>>>(X, Xbf, sq, posP, negP, sums);
  gemm_mine_kernel<<<NBLK, 64, 0, stream>>>(Xbf, sq, targets, posP, negP);
  local_dtw_kernel<<<NS / 4, 256, 0, stream>>>(LF, posP, negP, sums);
  finalize_kernel<<<1, 64, 0, stream>>>(sums, out);
}

// Round 6
// 222.015 us; speedup vs baseline: 1.4257x; 1.0982x over previous
//
#include <hip/hip_runtime.h>
#include <stdint.h>

#define NS 4096
#define DIM 2048
#define MARGINF 0.3f

typedef __bf16 bf16x8 __attribute__((ext_vector_type(8)));
typedef float floatx4 __attribute__((ext_vector_type(4)));

#define GLOBAL_AS __attribute__((address_space(1)))
#define LDS_AS __attribute__((address_space(3)))

__device__ __forceinline__ unsigned short f2bf_rne(float x) {
  unsigned u = __float_as_uint(x);
  u += 0x7FFFu + ((u >> 16) & 1u);
  return (unsigned short)(u >> 16);
}
__device__ __forceinline__ float bf2f(unsigned short b) {
  return __uint_as_float(((unsigned)b) << 16);
}

// ---------------- kernel 1: fp32 -> bf16 convert + row norms + init ----------------
__global__ __launch_bounds__(256) void prep_kernel(
    const float* __restrict__ X, unsigned short* __restrict__ Xbf,
    float* __restrict__ sq, unsigned long long* __restrict__ posP,
    unsigned long long* __restrict__ negP, float* __restrict__ sums) {
  const int row = blockIdx.x;
  const int t = threadIdx.x;
  const float4* xr = (const float4*)(X + (size_t)row * DIM);
  ushort4* br = (ushort4*)(Xbf + (size_t)row * DIM);
  float s = 0.f;
#pragma unroll
  for (int it = 0; it < 2; ++it) {
    int i = t + it * 256;
    float4 v = xr[i];
    ushort4 o;
    o.x = f2bf_rne(v.x); o.y = f2bf_rne(v.y);
    o.z = f2bf_rne(v.z); o.w = f2bf_rne(v.w);
    // accumulate norm of the ROUNDED values so d2 is consistent with the MFMA dot
    float b0 = bf2f(o.x), b1 = bf2f(o.y), b2 = bf2f(o.z), b3 = bf2f(o.w);
    s += b0 * b0 + b1 * b1 + b2 * b2 + b3 * b3;
    br[i] = o;
  }
#pragma unroll
  for (int m = 32; m > 0; m >>= 1) s += __shfl_down(s, m, 64);
  __shared__ float ls[4];
  const int w = t >> 6, lane = t & 63;
  if (lane == 0) ls[w] = s;
  __syncthreads();
  if (t == 0) {
    sq[row] = ls[0] + ls[1] + ls[2] + ls[3];
    posP[row] = 0ULL;              // max-init (dist >= 0, self always positive)
    negP[row] = ~0ULL;             // min-init
    if (row == 0) { sums[0] = 0.f; sums[1] = 0.f; }
  }
}

// ---------------- kernel 2: bf16 MFMA Gram GEMM, BK=64, XCD-clustered tiles ----------------
#define BM 128
#define BN 128
#define BKE 64           // K elems staged per iter (128 B per row)
#define NT 32
#define NBLK (NT * (NT + 1) / 2)   // 528 upper-tri tiles = 8 XCDs x 66

__device__ __forceinline__ void async16(const void* g, void* l) {
  __builtin_amdgcn_global_load_lds((GLOBAL_AS unsigned int*)g, (LDS_AS unsigned int*)l,
                                   16, 0, 0);
}

__global__ __launch_bounds__(256) void gemm_mine_kernel(
    const unsigned short* __restrict__ Xbf, const float* __restrict__ sq,
    const int* __restrict__ targets,
    unsigned long long* __restrict__ posP, unsigned long long* __restrict__ negP) {
  // XCD-clustered tile order: blockIdx % 8 selects the XCD [heuristic]; give each
  // XCD 66 consecutive ty-major tiles so its L2 sees a narrow A-row band.
  const int t = (blockIdx.x & 7) * 66 + (blockIdx.x >> 3);
  // invert t -> (ty, tx) on the upper triangle: cum(y) = y*(65-y)/2
  int ty = (int)((65.0f - sqrtf((float)(4225 - 8 * t))) * 0.5f);
  while ((ty + 1) * (65 - (ty + 1)) / 2 <= t) ++ty;
  while (ty * (65 - ty) / 2 > t) --ty;
  const int tx = ty + (t - ty * (65 - ty) / 2);
  const int r0 = ty * BM;
  const int c0 = tx * BN;

  // [128 rows][64 elems] per matrix, 16 KB each
  __shared__ __align__(16) unsigned short Ab[BM * BKE];
  __shared__ __align__(16) unsigned short Bb[BN * BKE];
  const int tid = threadIdx.x;
  const int lane = tid & 63;
  const int w = tid >> 6;          // wave 0..3
  const int wm = w >> 1, wn = w & 1;
  const int quad = lane >> 4;
  const int ml = lane & 15;

  floatx4 acc[4][4];
#pragma unroll
  for (int i = 0; i < 4; ++i)
#pragma unroll
    for (int j = 0; j < 4; ++j)
#pragma unroll
      for (int k = 0; k < 4; ++k) acc[i][j][k] = 0.f;

  // Staging, BK=64: row = 128 B = 8 chunks of 16 B. XOR swizzle: chunk c of row R
  // lives at slot c ^ (R&7). DMA writes wave-uniform base + lane*16, i.e. lane ->
  // (row lane>>3, slot lane&7); so lane FETCHES global chunk (lane&7)^((lane>>3)&7).
  // Each async16 covers 8 rows x 128 B; wave w stages rows w*32..w*32+31 (4 instrs/matrix).
  const int r_rel = lane >> 3;            // row within 8-row group
  const int c_g = (lane & 7) ^ r_rel;     // global chunk to fetch (8 elems each)
  const unsigned short* gA = Xbf + (size_t)(r0 + w * 32 + r_rel) * DIM + c_g * 8;
  const unsigned short* gB = Xbf + (size_t)(c0 + w * 32 + r_rel) * DIM + c_g * 8;
  unsigned short* lA = Ab + w * 32 * BKE;   // wave-uniform
  unsigned short* lB = Bb + w * 32 * BKE;

  // fragment read: row R = i*16+ml, k-half h, logical chunk = h*4+quad,
  // slot = (h*4+quad) ^ (R&7) = (h*4+quad) ^ (ml&7)
  const int sx = ml & 7;

  for (int k0 = 0; k0 < DIM; k0 += BKE) {
    __syncthreads();
#pragma unroll
    for (int q = 0; q < 4; ++q)
      async16(gA + (size_t)(q * 8) * DIM + k0, lA + q * 8 * BKE);
#pragma unroll
    for (int q = 0; q < 4; ++q)
      async16(gB + (size_t)(q * 8) * DIM + k0, lB + q * 8 * BKE);
    __syncthreads();   // vmcnt(0) drain (m97 structure), now every 64 K-elems
#pragma unroll
    for (int h = 0; h < 2; ++h) {
      bf16x8 af[4], bfr[4];
#pragma unroll
      for (int i = 0; i < 4; ++i)
        af[i] = *(const bf16x8*)(Ab + ((wm * 64 + i * 16 + ml) * BKE) +
                                 (((h << 2) + quad) ^ sx) * 8);
#pragma unroll
      for (int j = 0; j < 4; ++j)
        bfr[j] = *(const bf16x8*)(Bb + ((wn * 64 + j * 16 + ml) * BKE) +
                                  (((h << 2) + quad) ^ sx) * 8);
#pragma unroll
      for (int i = 0; i < 4; ++i)
#pragma unroll
        for (int j = 0; j < 4; ++j)
          acc[i][j] = __builtin_amdgcn_mfma_f32_16x16x32_bf16(af[i], bfr[j], acc[i][j], 0, 0, 0);
    }
  }

  // epilogue A: row-direction mining (rows gr, cols gc).
  // C/D layout: col = lane&15, row = (lane>>4)*4 + reg  [m89/m91 verified]
  const int cl = ml;
  const int tr_base = r0 + wm * 64;
  const int tc_base = c0 + wn * 64;
#pragma unroll
  for (int i = 0; i < 4; ++i) {
#pragma unroll
    for (int rg = 0; rg < 4; ++rg) {
      const int gr = tr_base + i * 16 + quad * 4 + rg;
      const int tgt_r = targets[gr];
      const float sqr = sq[gr];
      unsigned long long pm = 0ULL;
      unsigned long long nm = ~0ULL;
#pragma unroll
      for (int j = 0; j < 4; ++j) {
        const int gc = tc_base + j * 16 + cl;
        const float dot = acc[i][j][rg];
        const float d2 = sqr + sq[gc] - 2.0f * dot;
        const float dist = sqrtf(fmaxf(d2, 1e-12f));
        const unsigned long long packed_hi = ((unsigned long long)__float_as_uint(dist)) << 32;
        if (targets[gc] == tgt_r) {
          // argmax first-index tiebreak: larger (4095-gc) == smaller gc wins on ties
          unsigned long long cand = packed_hi | (unsigned)(4095 - gc);
          pm = pm > cand ? pm : cand;
        } else {
          unsigned long long cand = packed_hi | (unsigned)gc;
          nm = nm < cand ? nm : cand;
        }
      }
#pragma unroll
      for (int m = 1; m < 16; m <<= 1) {
        unsigned long long pmo = __shfl_xor(pm, m, 64);
        unsigned long long nmo = __shfl_xor(nm, m, 64);
        pm = pm > pmo ? pm : pmo;
        nm = nm < nmo ? nm : nmo;
      }
      if (cl == 0) {
        atomicMax(&posP[gr], pm);
        atomicMin(&negP[gr], nm);
      }
    }
  }

  // epilogue B: transposed mining for off-diagonal blocks — bit-exact symmetric reuse
  if (tx != ty) {
#pragma unroll
    for (int j = 0; j < 4; ++j) {
      const int gc = tc_base + j * 16 + cl;
      const int tgt_c = targets[gc];
      const float sqc = sq[gc];
      unsigned long long pm = 0ULL;
      unsigned long long nm = ~0ULL;
#pragma unroll
      for (int i = 0; i < 4; ++i) {
#pragma unroll
        for (int rg = 0; rg < 4; ++rg) {
          const int gr = tr_base + i * 16 + quad * 4 + rg;
          const float dot = acc[i][j][rg];
          const float d2 = sq[gr] + sqc - 2.0f * dot;
          const float dist = sqrtf(fmaxf(d2, 1e-12f));
          const unsigned long long packed_hi = ((unsigned long long)__float_as_uint(dist)) << 32;
          if (targets[gr] == tgt_c) {
            unsigned long long cand = packed_hi | (unsigned)(4095 - gr);
            pm = pm > cand ? pm : cand;
          } else {
            unsigned long long cand = packed_hi | (unsigned)gr;
            nm = nm < cand ? nm : cand;
          }
        }
      }
#pragma unroll
      for (int m = 16; m < 64; m <<= 1) {
        unsigned long long pmo = __shfl_xor(pm, m, 64);
        unsigned long long nmo = __shfl_xor(nm, m, 64);
        pm = pm > pmo ? pm : pmo;
        nm = nm < nmo ? nm : nmo;
      }
      if (quad == 0) {
        atomicMax(&posP[gc], pm);
        atomicMin(&negP[gc], nm);
      }
    }
  }
}

// ---------------- kernel 3: local DTW distances + both loss sums ----------------
__global__ __launch_bounds__(256) void local_dtw_kernel(
    const float* __restrict__ LF, const unsigned long long* __restrict__ posP,
    const unsigned long long* __restrict__ negP, float* __restrict__ sums) {
  __shared__ float bufA[4][1024];
  __shared__ float bufP[4][1024];
  __shared__ float bufN[4][1024];
  __shared__ float dmP[4][64];
  __shared__ float dmN[4][64];
  __shared__ float gterms[4], lterms[4];
  const int w = threadIdx.x >> 6, lane = threadIdx.x & 63;
  const int a = blockIdx.x * 4 + w;
  const unsigned long long pp = posP[a];
  const unsigned long long nn = negP[a];
  const int p_ind = 4095 - (int)(pp & 0xFFFFFFFFULL);
  const int n_ind = (int)(nn & 0xFFFFFFFFULL);
  const float dist_ap = __uint_as_float((unsigned)(pp >> 32));
  const float dist_an = __uint_as_float((unsigned)(nn >> 32));

  const float4* ga = (const float4*)(LF + (size_t)a * 1024);
  const float4* gp = (const float4*)(LF + (size_t)p_ind * 1024);
  const float4* gn = (const float4*)(LF + (size_t)n_ind * 1024);
  float4* la = (float4*)bufA[w];
  float4* lp = (float4*)bufP[w];
  float4* ln_ = (float4*)bufN[w];
#pragma unroll
  for (int i = 0; i < 4; ++i) {
    la[lane + i * 64] = ga[lane + i * 64];
    lp[lane + i * 64] = gp[lane + i * 64];
    ln_[lane + i * 64] = gn[lane + i * 64];
  }
  __syncthreads();
  // lane -> (t1, t2) pair of the 8x8 cross-distance matrix; layout is [d][t] (stride 8)
  const int t1 = lane >> 3, t2 = lane & 7;
  float sp = 0.f, sn = 0.f;
#pragma unroll 8
  for (int d = 0; d < 128; ++d) {
    float xa = bufA[w][d * 8 + t1];
    float xp = bufP[w][d * 8 + t2];
    float xn = bufN[w][d * 8 + t2];
    float e1 = xa - xp; sp += e1 * e1;
    float e2 = xa - xn; sn += e2 * e2;
  }
  float ddp = sqrtf(fmaxf(sp, 1e-12f));
  float ddn = sqrtf(fmaxf(sn, 1e-12f));
  dmP[w][lane] = tanhf(0.5f * ddp);   // == (e^d-1)/(e^d+1)
  dmN[w][lane] = tanhf(0.5f * ddn);
  __syncthreads();
  if (lane == 0) {
    float ap, an;
    {
      const float* dm = dmP[w];
      float row[8];
      row[0] = dm[0];
#pragma unroll
      for (int j = 1; j < 8; ++j) row[j] = row[j - 1] + dm[j];
#pragma unroll
      for (int i = 1; i < 8; ++i) {
        row[0] = row[0] + dm[i * 8];
#pragma unroll
        for (int j = 1; j < 8; ++j) row[j] = fminf(row[j], row[j - 1]) + dm[i * 8 + j];
      }
      ap = row[7];
    }
    {
      const float* dm = dmN[w];
      float row[8];
      row[0] = dm[0];
#pragma unroll
      for (int j = 1; j < 8; ++j) row[j] = row[j - 1] + dm[j];
#pragma unroll
      for (int i = 1; i < 8; ++i) {
        row[0] = row[0] + dm[i * 8];
#pragma unroll
        for (int j = 1; j < 8; ++j) row[j] = fminf(row[j], row[j - 1]) + dm[i * 8 + j];
      }
      an = row[7];
    }
    gterms[w] = fmaxf(dist_ap - dist_an + MARGINF, 0.f);
    lterms[w] = fmaxf(ap - an + MARGINF, 0.f);
  }
  __syncthreads();
  if (threadIdx.x == 0) {
    atomicAdd(&sums[0], gterms[0] + gterms[1] + gterms[2] + gterms[3]);
    atomicAdd(&sums[1], lterms[0] + lterms[1] + lterms[2] + lterms[3]);
  }
}

// ---------------- kernel 4: finalize ----------------
__global__ void finalize_kernel(const float* __restrict__ sums, float* __restrict__ out) {
  if (threadIdx.x == 0) {
    out[0] = sums[0] * (1.0f / 4096.0f);
    out[1] = sums[1] * (1.0f / 4096.0f);
  }
}

extern "C" void kernel_launch(void* const* d_in, const int* in_sizes, int n_in,
                              void* d_out, int out_size, void* d_ws, size_t ws_size,
                              hipStream_t stream) {
  const float* X = (const float*)d_in[0];
  const int* targets = (const int*)d_in[1];
  const float* LF = (const float*)d_in[2];
  float* out = (float*)d_out;

  char* ws = (char*)d_ws;
  size_t off = 0;
  unsigned short* Xbf = (unsigned short*)(ws + off); off += (size_t)NS * DIM * 2;  // 16 MB
  float* sq = (float*)(ws + off); off += (size_t)NS * 4;
  off = (off + 255) & ~(size_t)255;
  unsigned long long* posP = (unsigned long long*)(ws + off); off += (size_t)NS * 8;
  unsigned long long* negP = (unsigned long long*)(ws + off); off += (size_t)NS * 8;
  float* sums = (float*)(ws + off); off += 256;

  prep_kernel<<<NS, 256, 0, stream>>>(X, Xbf, sq, posP, negP, sums);
  gemm_mine_kernel<<<NBLK, 256, 0, stream>>>(Xbf, sq, targets, posP, negP);
  local_dtw_kernel<<<NS / 4, 256, 0, stream>>>(LF, posP, negP, sums);
  finalize_kernel<<<1, 64, 0, stream>>>(sums, out);
}